// Round 2
// baseline (45.932 us; speedup 1.0000x reference)
//
#include <hip/hip_runtime.h>

#define K_SAMP 256
#define D_HID 64
#define SCALER_FE 7.0f

__global__ __launch_bounds__(256, 4)
void volrend_kernel(const float* __restrict__ ray_start,
                    const float* __restrict__ ray_dir,
                    const float* __restrict__ depth,
                    const float* __restrict__ dists,
                    const int*   __restrict__ vidx,
                    const float* __restrict__ vcol_tab,
                    const float* __restrict__ W1,
                    const float* __restrict__ b1,
                    const float* __restrict__ w_sigma,
                    const float* __restrict__ b_sigma,
                    const float* __restrict__ W_tex,
                    const float* __restrict__ b_tex,
                    float* __restrict__ out_colors,
                    float* __restrict__ out_depths,
                    float* __restrict__ out_missed,
                    float* __restrict__ out_probs) {
    __shared__ float sW1[6 * D_HID];   // W1[f][d], row-major (6,64)
    __shared__ float sb1[D_HID];
    __shared__ float sws[D_HID];       // w_sigma
    __shared__ float sWt[D_HID * 3];   // W_tex[d][c]
    __shared__ float swsum[4];         // per-wave scan totals
    __shared__ float sred[4 * 5];      // per-wave reduction partials

    const int ray = blockIdx.x;
    const int k   = threadIdx.x;          // sample index within ray
    const int lane = k & 63;
    const int wid  = k >> 6;

    // --- stage weights into LDS (cooperative; grid-stride over 384 elems) ---
    for (int i = k; i < 6 * D_HID; i += K_SAMP) sW1[i] = W1[i];
    if (k < D_HID) { sb1[k] = b1[k]; sws[k] = w_sigma[k]; }
    if (k < 3 * D_HID) sWt[k] = W_tex[k];
    __syncthreads();

    // --- per-sample inputs ---
    const float rs0 = ray_start[ray * 3 + 0];
    const float rs1 = ray_start[ray * 3 + 1];
    const float rs2 = ray_start[ray * 3 + 2];
    const float rd0 = ray_dir[ray * 3 + 0];
    const float rd1 = ray_dir[ray * 3 + 1];
    const float rd2 = ray_dir[ray * 3 + 2];

    const float dep = depth[ray * K_SAMP + k];
    const float dst = dists[ray * K_SAMP + k];
    const int   vi  = vidx[ray * K_SAMP + k];
    const bool  msk = (vi != -1);

    const float f0 = rs0 + rd0 * dep;
    const float f1 = rs1 + rd1 * dep;
    const float f2 = rs2 + rd2 * dep;

    // --- tiny MLP: h = relu(feat @ W1 + b1); sigma = h@w_sigma; tex = h@W_tex ---
    float sigma = b_sigma[0];
    float t0 = b_tex[0], t1 = b_tex[1], t2 = b_tex[2];
    #pragma unroll 8
    for (int d = 0; d < D_HID; ++d) {
        float h = sb1[d]
                + f0  * sW1[0 * D_HID + d]
                + f1  * sW1[1 * D_HID + d]
                + f2  * sW1[2 * D_HID + d]
                + rd0 * sW1[3 * D_HID + d]
                + rd1 * sW1[4 * D_HID + d]
                + rd2 * sW1[5 * D_HID + d];
        h = fmaxf(h, 0.0f);
        sigma += h * sws[d];
        t0 += h * sWt[d * 3 + 0];
        t1 += h * sWt[d * 3 + 1];
        t2 += h * sWt[d * 3 + 2];
    }

    // --- free energy + voxel color, masked ---
    float fe = 0.0f;
    if (msk) {
        fe = fmaxf(sigma, 0.0f) * dst * SCALER_FE;
        const int b = vi * 3;
        t0 += vcol_tab[b + 0];
        t1 += vcol_tab[b + 1];
        t2 += vcol_tab[b + 2];
    } else {
        t0 = 0.0f; t1 = 0.0f; t2 = 0.0f;
    }

    // --- exclusive prefix sum of fe across the block (shifted cumsum) ---
    float x = fe;
    #pragma unroll
    for (int off = 1; off < 64; off <<= 1) {
        float v = __shfl_up(x, off, 64);
        if (lane >= off) x += v;
    }
    if (lane == 63) swsum[wid] = x;
    __syncthreads();
    float wpre = 0.0f;
    #pragma unroll
    for (int w = 0; w < 4; ++w) {
        if (w < wid) wpre += swsum[w];
    }
    const float excl = wpre + x - fe;    // sum of fe[j] for j < k

    const float a = 1.0f - __expf(-fe);  // masked: fe=0 -> a=0 -> p=0
    const float bcoef = __expf(-excl);
    const float p = a * bcoef;

    // --- reductions: sum(p), sum(dep*p), sum(tex_c*p) ---
    float sp = p;
    float sd = dep * p;
    float c0 = t0 * p;
    float c1 = t1 * p;
    float c2 = t2 * p;
    #pragma unroll
    for (int off = 32; off > 0; off >>= 1) {
        sp += __shfl_down(sp, off, 64);
        sd += __shfl_down(sd, off, 64);
        c0 += __shfl_down(c0, off, 64);
        c1 += __shfl_down(c1, off, 64);
        c2 += __shfl_down(c2, off, 64);
    }
    if (lane == 0) {
        sred[wid * 5 + 0] = sp;
        sred[wid * 5 + 1] = sd;
        sred[wid * 5 + 2] = c0;
        sred[wid * 5 + 3] = c1;
        sred[wid * 5 + 4] = c2;
    }
    __syncthreads();
    if (k == 0) {
        float tp = 0.f, td = 0.f, tc0 = 0.f, tc1 = 0.f, tc2 = 0.f;
        #pragma unroll
        for (int w = 0; w < 4; ++w) {
            tp  += sred[w * 5 + 0];
            td  += sred[w * 5 + 1];
            tc0 += sred[w * 5 + 2];
            tc1 += sred[w * 5 + 3];
            tc2 += sred[w * 5 + 4];
        }
        out_colors[ray * 3 + 0] = tc0;
        out_colors[ray * 3 + 1] = tc1;
        out_colors[ray * 3 + 2] = tc2;
        out_depths[ray] = td;
        out_missed[ray] = 1.0f - tp;
    }
    out_probs[ray * K_SAMP + k] = p;
}

extern "C" void kernel_launch(void* const* d_in, const int* in_sizes, int n_in,
                              void* d_out, int out_size, void* d_ws, size_t ws_size,
                              hipStream_t stream) {
    const float* ray_start  = (const float*)d_in[0];
    const float* ray_dir    = (const float*)d_in[1];
    const float* depth      = (const float*)d_in[2];
    const float* dists      = (const float*)d_in[3];
    const int*   vidx       = (const int*)d_in[4];
    const float* vcol       = (const float*)d_in[5];
    const float* W1         = (const float*)d_in[6];
    const float* b1         = (const float*)d_in[7];
    const float* w_sigma    = (const float*)d_in[8];
    const float* b_sigma    = (const float*)d_in[9];
    const float* W_tex      = (const float*)d_in[10];
    const float* b_tex      = (const float*)d_in[11];

    const int N = in_sizes[0] / 3;       // 4096 rays
    // output layout: colors[N*3] | depths[N] | missed[N] | probs[N*K]
    float* out        = (float*)d_out;
    float* out_colors = out;
    float* out_depths = out + (size_t)N * 3;
    float* out_missed = out + (size_t)N * 3 + N;
    float* out_probs  = out + (size_t)N * 3 + 2 * (size_t)N;

    volrend_kernel<<<N, K_SAMP, 0, stream>>>(
        ray_start, ray_dir, depth, dists, vidx, vcol,
        W1, b1, w_sigma, b_sigma, W_tex, b_tex,
        out_colors, out_depths, out_missed, out_probs);
}

// Round 3
// 45.343 us; speedup vs baseline: 1.0130x; 1.0130x over previous
//
#include <hip/hip_runtime.h>

#define K_SAMP 256
#define D_HID 64
#define SCALER_FE 7.0f

__global__ __launch_bounds__(256, 8)
void volrend_kernel(const float* __restrict__ ray_start,
                    const float* __restrict__ ray_dir,
                    const float* __restrict__ depth,
                    const float* __restrict__ dists,
                    const int*   __restrict__ vidx,
                    const float* __restrict__ vcol_tab,
                    const float* __restrict__ W1,
                    const float* __restrict__ b1,
                    const float* __restrict__ w_sigma,
                    const float* __restrict__ b_sigma,
                    const float* __restrict__ W_tex,
                    const float* __restrict__ b_tex,
                    float* __restrict__ out_colors,
                    float* __restrict__ out_depths,
                    float* __restrict__ out_missed,
                    float* __restrict__ out_probs) {
    __shared__ float swsum[4];         // per-wave scan totals
    __shared__ float sred[4 * 5];      // per-wave reduction partials

    const int ray = blockIdx.x;
    const int k   = threadIdx.x;          // sample index within ray
    const int lane = k & 63;
    const int wid  = k >> 6;

    // --- per-ray inputs (uniform -> scalar loads) ---
    const float rs0 = ray_start[ray * 3 + 0];
    const float rs1 = ray_start[ray * 3 + 1];
    const float rs2 = ray_start[ray * 3 + 2];
    const float rd0 = ray_dir[ray * 3 + 0];
    const float rd1 = ray_dir[ray * 3 + 1];
    const float rd2 = ray_dir[ray * 3 + 2];

    // --- per-sample inputs (coalesced vector loads) ---
    const float dep = depth[ray * K_SAMP + k];
    const float dst = dists[ray * K_SAMP + k];
    const int   vi  = vidx[ray * K_SAMP + k];
    const bool  msk = (vi != -1);

    const float f0 = rs0 + rd0 * dep;
    const float f1 = rs1 + rd1 * dep;
    const float f2 = rs2 + rd2 * dep;

    // --- tiny MLP; all weight indices are wave-uniform -> s_load (scalar pipe),
    //     v_fma with SGPR operand. No LDS, no per-lane weight traffic. ---
    float sigma = b_sigma[0];
    float t0 = b_tex[0], t1 = b_tex[1], t2 = b_tex[2];
    #pragma unroll
    for (int d = 0; d < D_HID; ++d) {
        float h = b1[d];
        h = fmaf(f0,  W1[0 * D_HID + d], h);
        h = fmaf(f1,  W1[1 * D_HID + d], h);
        h = fmaf(f2,  W1[2 * D_HID + d], h);
        h = fmaf(rd0, W1[3 * D_HID + d], h);
        h = fmaf(rd1, W1[4 * D_HID + d], h);
        h = fmaf(rd2, W1[5 * D_HID + d], h);
        h = fmaxf(h, 0.0f);
        sigma = fmaf(h, w_sigma[d], sigma);
        t0 = fmaf(h, W_tex[d * 3 + 0], t0);
        t1 = fmaf(h, W_tex[d * 3 + 1], t1);
        t2 = fmaf(h, W_tex[d * 3 + 2], t2);
    }

    // --- free energy + voxel color, masked ---
    float fe = 0.0f;
    if (msk) {
        fe = fmaxf(sigma, 0.0f) * dst * SCALER_FE;
        const int b = vi * 3;
        t0 += vcol_tab[b + 0];
        t1 += vcol_tab[b + 1];
        t2 += vcol_tab[b + 2];
    } else {
        t0 = 0.0f; t1 = 0.0f; t2 = 0.0f;
    }

    // --- exclusive prefix sum of fe across the block (shifted cumsum) ---
    float x = fe;
    #pragma unroll
    for (int off = 1; off < 64; off <<= 1) {
        float v = __shfl_up(x, off, 64);
        if (lane >= off) x += v;
    }
    if (lane == 63) swsum[wid] = x;
    __syncthreads();
    float wpre = 0.0f;
    #pragma unroll
    for (int w = 0; w < 4; ++w) {
        if (w < wid) wpre += swsum[w];
    }
    const float excl = wpre + x - fe;    // sum of fe[j] for j < k

    const float a = 1.0f - __expf(-fe);  // masked: fe=0 -> a=0 -> p=0
    const float bcoef = __expf(-excl);
    const float p = a * bcoef;

    // --- reductions: sum(p), sum(dep*p), sum(tex_c*p) ---
    float sp = p;
    float sd = dep * p;
    float c0 = t0 * p;
    float c1 = t1 * p;
    float c2 = t2 * p;
    #pragma unroll
    for (int off = 32; off > 0; off >>= 1) {
        sp += __shfl_down(sp, off, 64);
        sd += __shfl_down(sd, off, 64);
        c0 += __shfl_down(c0, off, 64);
        c1 += __shfl_down(c1, off, 64);
        c2 += __shfl_down(c2, off, 64);
    }
    if (lane == 0) {
        sred[wid * 5 + 0] = sp;
        sred[wid * 5 + 1] = sd;
        sred[wid * 5 + 2] = c0;
        sred[wid * 5 + 3] = c1;
        sred[wid * 5 + 4] = c2;
    }
    __syncthreads();
    if (k == 0) {
        float tp = 0.f, td = 0.f, tc0 = 0.f, tc1 = 0.f, tc2 = 0.f;
        #pragma unroll
        for (int w = 0; w < 4; ++w) {
            tp  += sred[w * 5 + 0];
            td  += sred[w * 5 + 1];
            tc0 += sred[w * 5 + 2];
            tc1 += sred[w * 5 + 3];
            tc2 += sred[w * 5 + 4];
        }
        out_colors[ray * 3 + 0] = tc0;
        out_colors[ray * 3 + 1] = tc1;
        out_colors[ray * 3 + 2] = tc2;
        out_depths[ray] = td;
        out_missed[ray] = 1.0f - tp;
    }
    out_probs[ray * K_SAMP + k] = p;
}

extern "C" void kernel_launch(void* const* d_in, const int* in_sizes, int n_in,
                              void* d_out, int out_size, void* d_ws, size_t ws_size,
                              hipStream_t stream) {
    const float* ray_start  = (const float*)d_in[0];
    const float* ray_dir    = (const float*)d_in[1];
    const float* depth      = (const float*)d_in[2];
    const float* dists      = (const float*)d_in[3];
    const int*   vidx       = (const int*)d_in[4];
    const float* vcol       = (const float*)d_in[5];
    const float* W1         = (const float*)d_in[6];
    const float* b1         = (const float*)d_in[7];
    const float* w_sigma    = (const float*)d_in[8];
    const float* b_sigma    = (const float*)d_in[9];
    const float* W_tex      = (const float*)d_in[10];
    const float* b_tex      = (const float*)d_in[11];

    const int N = in_sizes[0] / 3;       // 4096 rays
    // output layout: colors[N*3] | depths[N] | missed[N] | probs[N*K]
    float* out        = (float*)d_out;
    float* out_colors = out;
    float* out_depths = out + (size_t)N * 3;
    float* out_missed = out + (size_t)N * 3 + N;
    float* out_probs  = out + (size_t)N * 3 + 2 * (size_t)N;

    volrend_kernel<<<N, K_SAMP, 0, stream>>>(
        ray_start, ray_dir, depth, dists, vidx, vcol,
        W1, b1, w_sigma, b_sigma, W_tex, b_tex,
        out_colors, out_depths, out_missed, out_probs);
}